// Round 1
// baseline (141.167 us; speedup 1.0000x reference)
//
#include <hip/hip_runtime.h>

// Problem constants (from reference): B = 4_194_304 = 2^22 rows.
// Per row: inputs[3] f32, targets[3] i32, cycle_state i32, weights[7] f32 shared.
// out = mean_B( sw * (0.5*(d0+d1) + d2) ) + sum_B( range_penalty )
//
// Memory-bound: 112 MB read -> ~18 us at 6.3 TB/s.

#define NBLOCKS 2048
#define NTHREADS 256

// 2^-22 : exact power-of-two scaling for the mean over B
#define INV_B 2.384185791015625e-07f

__device__ __forceinline__ double block_reduce(double acc) {
    // wave-64 shuffle reduce
    #pragma unroll
    for (int o = 32; o > 0; o >>= 1) acc += __shfl_down(acc, o, 64);
    __shared__ double sacc[NTHREADS / 64];
    const int lane = threadIdx.x & 63;
    const int wave = threadIdx.x >> 6;
    if (lane == 0) sacc[wave] = acc;
    __syncthreads();
    double s = 0.0;
    if (threadIdx.x == 0) {
        #pragma unroll
        for (int w = 0; w < NTHREADS / 64; ++w) s += sacc[w];
    }
    return s;
}

__global__ __launch_bounds__(NTHREADS) void wmse_main(
    const float* __restrict__ inputs,   // [B,3]
    const int*   __restrict__ targets,  // [B,3]
    const int*   __restrict__ states,   // [B]
    const float* __restrict__ weights,  // [7]
    double*      __restrict__ partials, // [NBLOCKS]
    int nquads)                          // B/4
{
    __shared__ float w[8];
    if (threadIdx.x < 7) w[threadIdx.x] = weights[threadIdx.x];
    __syncthreads();

    const float4* __restrict__ in4 = (const float4*)inputs;
    const int4*   __restrict__ tg4 = (const int4*)targets;
    const int4*   __restrict__ st4 = (const int4*)states;

    double acc = 0.0;
    const int stride = gridDim.x * blockDim.x;
    for (int q = blockIdx.x * blockDim.x + threadIdx.x; q < nquads; q += stride) {
        // 4 rows = 12 floats / 12 ints -> 3 vec4 loads each, + 1 int4 of states
        float4 a = in4[3 * q + 0];
        float4 b = in4[3 * q + 1];
        float4 c = in4[3 * q + 2];
        int4  ta = tg4[3 * q + 0];
        int4  tb = tg4[3 * q + 1];
        int4  tc = tg4[3 * q + 2];
        int4   s = st4[q];

        float fin[12] = {a.x, a.y, a.z, a.w, b.x, b.y, b.z, b.w, c.x, c.y, c.z, c.w};
        int   tgt[12] = {ta.x, ta.y, ta.z, ta.w, tb.x, tb.y, tb.z, tb.w, tc.x, tc.y, tc.z, tc.w};
        int    st[4]  = {s.x, s.y, s.z, s.w};

        #pragma unroll
        for (int r = 0; r < 4; ++r) {
            const float i0 = fin[3 * r + 0];
            const float i1 = fin[3 * r + 1];
            const float i2 = fin[3 * r + 2];
            const int   t2i = tgt[3 * r + 2];
            const float t0 = (float)tgt[3 * r + 0];   // exact: < 2^24
            const float t1 = (float)tgt[3 * r + 1];
            const float t2 = (float)t2i;

            const float sw = w[t2i / 100 - 1];        // t2i in {100..700}

            const float d0 = (i0 - t0) * (i0 - t0);
            const float d1 = (i1 - t1) * (i1 - t1);
            const float d2 = (i2 - t2) * (i2 - t2);
            const float mse = sw * (0.5f * (d0 + d1) + d2);

            // range tables (idx = state-1, in [0,21))
            const int idx = st[r] - 1;
            const float lo02 = (idx == 3) ? 6400.0f
                             : ((idx >= 4 && idx <= 7) ? 6000.0f : 11500.0f);
            const float hi02 = 12000.0f;
            const float lo03 = 2200.0f;
            const float hi03 = (idx == 7) ? 13000.0f : 2500.0f;

            float p = 0.0f;
            {
                const float dl = t0 - lo02, dh = t0 - hi02;
                p += (t0 < lo02) ? dl * dl : 0.0f;
                p += (t0 > hi02) ? dh * dh : 0.0f;
            }
            {
                const float dl = t1 - lo03, dh = t1 - hi03;
                p += (t1 < lo03) ? dl * dl : 0.0f;
                p += (t1 > hi03) ? dh * dh : 0.0f;
            }

            // mse * 2^-22 is exact scaling; accumulate in double
            acc += (double)(mse * INV_B) + (double)p;
        }
    }

    const double s = block_reduce(acc);
    if (threadIdx.x == 0) partials[blockIdx.x] = s;
}

__global__ __launch_bounds__(NTHREADS) void wmse_final(
    const double* __restrict__ partials, int n, float* __restrict__ out)
{
    double acc = 0.0;
    for (int i = threadIdx.x; i < n; i += NTHREADS) acc += partials[i];
    const double s = block_reduce(acc);
    if (threadIdx.x == 0) out[0] = (float)s;
}

extern "C" void kernel_launch(void* const* d_in, const int* in_sizes, int n_in,
                              void* d_out, int out_size, void* d_ws, size_t ws_size,
                              hipStream_t stream) {
    const float* inputs  = (const float*)d_in[0];   // [B,3] f32
    const int*   targets = (const int*)  d_in[1];   // [B,3] i32
    const int*   states  = (const int*)  d_in[2];   // [B]   i32
    const float* weights = (const float*)d_in[3];   // [7]   f32

    const int B = in_sizes[2];        // cycle_states is [B]
    const int nquads = B / 4;         // B = 2^22, divisible by 4

    double* partials = (double*)d_ws; // NBLOCKS * 8 bytes (<< ws_size)
    float*  out      = (float*)d_out;

    wmse_main<<<NBLOCKS, NTHREADS, 0, stream>>>(inputs, targets, states, weights,
                                                partials, nquads);
    wmse_final<<<1, NTHREADS, 0, stream>>>(partials, NBLOCKS, out);
}